// Round 1
// baseline (1605.248 us; speedup 1.0000x reference)
//
#include <hip/hip_runtime.h>
#include <hip/hip_bf16.h>
#include <cstdint>
#include <cstddef>

#define S_LEN 2048
#define HID   2560
#define NHQ   8
#define NKVH  4
#define DH    256
#define QKV_N 4096   // (NH + 2*NKV) * D
#define ATT_N 2048   // NH * D
#define WIN   1023
#define SCALE 0.0625f

// ---------------- fp32 GEMM: C[M,N] = A[M,K] @ B[K,N], row-major ----------------
// BM=BN=128, BK=16, 256 threads, 8x8 micro-tile per thread (split 4+4 at +64).
__global__ __launch_bounds__(256) void gemm_f32(const float* __restrict__ A,
                                                const float* __restrict__ B,
                                                float* __restrict__ C,
                                                int M, int N, int K) {
  __shared__ float As[16][132];   // transposed A tile, padded (+4) for banks
  __shared__ float Bs[16][128];
  const int tid = threadIdx.x;
  const int tx  = tid & 15;
  const int ty  = tid >> 4;
  const int bm  = blockIdx.y * 128;
  const int bn  = blockIdx.x * 128;

  const int arow = tid >> 2;          // 0..63 (+64)
  const int acol = (tid & 3) << 2;    // 0,4,8,12
  const int brow = tid >> 5;          // 0..7 (+8)
  const int bcol = (tid & 31) << 2;   // 0..124

  float acc[2][2][4][4] = {};

  for (int k0 = 0; k0 < K; k0 += 16) {
    float4 a0 = *(const float4*)(A + (size_t)(bm + arow)      * K + k0 + acol);
    float4 a1 = *(const float4*)(A + (size_t)(bm + arow + 64) * K + k0 + acol);
    float4 b0 = *(const float4*)(B + (size_t)(k0 + brow)     * N + bn + bcol);
    float4 b1 = *(const float4*)(B + (size_t)(k0 + brow + 8) * N + bn + bcol);
    As[acol + 0][arow] = a0.x; As[acol + 1][arow] = a0.y;
    As[acol + 2][arow] = a0.z; As[acol + 3][arow] = a0.w;
    As[acol + 0][arow + 64] = a1.x; As[acol + 1][arow + 64] = a1.y;
    As[acol + 2][arow + 64] = a1.z; As[acol + 3][arow + 64] = a1.w;
    *(float4*)(&Bs[brow][bcol])     = b0;
    *(float4*)(&Bs[brow + 8][bcol]) = b1;
    __syncthreads();
    #pragma unroll
    for (int kk = 0; kk < 16; ++kk) {
      float av[2][4], bv[2][4];
      *(float4*)av[0] = *(const float4*)(&As[kk][ty * 4]);
      *(float4*)av[1] = *(const float4*)(&As[kk][ty * 4 + 64]);
      *(float4*)bv[0] = *(const float4*)(&Bs[kk][tx * 4]);
      *(float4*)bv[1] = *(const float4*)(&Bs[kk][tx * 4 + 64]);
      #pragma unroll
      for (int i = 0; i < 2; ++i)
        #pragma unroll
        for (int p = 0; p < 4; ++p)
          #pragma unroll
          for (int j = 0; j < 2; ++j)
            #pragma unroll
            for (int q = 0; q < 4; ++q)
              acc[i][j][p][q] = fmaf(av[i][p], bv[j][q], acc[i][j][p][q]);
    }
    __syncthreads();
  }
  #pragma unroll
  for (int i = 0; i < 2; ++i)
    #pragma unroll
    for (int p = 0; p < 4; ++p) {
      const size_t row = (size_t)(bm + ty * 4 + i * 64 + p);
      #pragma unroll
      for (int j = 0; j < 2; ++j) {
        float4 o = make_float4(acc[i][j][p][0], acc[i][j][p][1],
                               acc[i][j][p][2], acc[i][j][p][3]);
        *(float4*)(C + row * N + bn + tx * 4 + j * 64) = o;
      }
    }
}

// ---------------- fused per-head RMSNorm + RoPE, in-place on qkv ----------------
// One wave per (s, head) row of 256. Rows 0..S*12-1: c = row%12; c<8 -> Q head c,
// else K head c-8. V columns untouched.
__global__ __launch_bounds__(256) void qk_norm_rope(float* __restrict__ qkv,
                                                    const float* __restrict__ cosp,
                                                    const float* __restrict__ sinp,
                                                    const float* __restrict__ qw,
                                                    const float* __restrict__ kw) {
  const int lane = threadIdx.x & 63;
  const int wave = threadIdx.x >> 6;
  const int row  = blockIdx.x * 4 + wave;      // 0..24575
  const int s    = row / 12;
  const int c    = row % 12;
  float* p = qkv + (size_t)s * QKV_N + c * 256;

  float4 x = *(const float4*)(p + lane * 4);
  float ss = x.x * x.x + x.y * x.y + x.z * x.z + x.w * x.w;
  #pragma unroll
  for (int off = 32; off; off >>= 1) ss += __shfl_xor(ss, off);
  const float scale = rsqrtf(ss * (1.0f / 256.0f) + 1e-6f);

  const float* wp = (c < 8) ? qw : kw;
  float4 w4 = *(const float4*)(wp + lane * 4);
  float y0 = x.x * scale * (1.0f + w4.x);
  float y1 = x.y * scale * (1.0f + w4.y);
  float y2 = x.z * scale * (1.0f + w4.z);
  float y3 = x.w * scale * (1.0f + w4.w);

  // rotate_half partner: d and d^128 differ only in lane^32 (lane holds d=4*lane+j)
  float z0 = __shfl_xor(y0, 32);
  float z1 = __shfl_xor(y1, 32);
  float z2 = __shfl_xor(y2, 32);
  float z3 = __shfl_xor(y3, 32);
  const float sgn = (lane < 32) ? -1.0f : 1.0f;

  float4 c4 = *(const float4*)(cosp + (size_t)s * 256 + lane * 4);
  float4 s4 = *(const float4*)(sinp + (size_t)s * 256 + lane * 4);
  float4 o;
  o.x = y0 * c4.x + sgn * z0 * s4.x;
  o.y = y1 * c4.y + sgn * z1 * s4.y;
  o.z = y2 * c4.z + sgn * z2 * s4.z;
  o.w = y3 * c4.w + sgn * z3 * s4.w;
  *(float4*)(p + lane * 4) = o;
}

// ---------------- sliding-window GQA flash attention (fp32) ----------------
// Block: 256 thr = 4 waves; wave owns 8 consecutive q rows of one head.
// QK: lanes over keys (lane = key in 64-tile), Q read via wave-uniform (scalar) loads.
// PV: P staged in wave-private LDS, lanes over d (coalesced V).
__global__ __launch_bounds__(256) void attn_fwd(const float* __restrict__ qkv,
                                                float* __restrict__ attn_out) {
  __shared__ float p_lds[4][8][64];
  const int lane = threadIdx.x & 63;
  const int wave = __builtin_amdgcn_readfirstlane(threadIdx.x >> 6);
  const int head = blockIdx.y;
  const int kvh  = head >> 1;                 // rep = NH/NKV = 2
  const int rbase = blockIdx.x * 32 + wave * 8;

  const float* kbase = qkv + 2048 + kvh * 256;
  const float* vbase = qkv + 3072 + kvh * 256;
  const float* qbase = qkv + head * 256;

  float out[8][4] = {};
  float m_run[8], l_run[8];
  #pragma unroll
  for (int r = 0; r < 8; ++r) { m_run[r] = -3.0e38f; l_run[r] = 0.0f; }

  const int t_hi = rbase + 7;
  const int t_lo_raw = rbase - WIN;
  int t0 = (t_lo_raw < 0) ? 0 : (t_lo_raw & ~63);

  for (; t0 <= t_hi; t0 += 64) {
    const int t = t0 + lane;
    const int t_load = (t > S_LEN - 1) ? (S_LEN - 1) : t;

    // ---- QK^T: each lane computes dot(q_r, k_t) for r=0..7 ----
    float sacc[8] = {};
    const float* krow = kbase + (size_t)t_load * QKV_N;
    #pragma unroll 4
    for (int d4 = 0; d4 < 64; ++d4) {
      const float4 k4 = *(const float4*)(krow + d4 * 4);
      #pragma unroll
      for (int r = 0; r < 8; ++r) {
        const float4 q4 = *(const float4*)(qbase + (size_t)(rbase + r) * QKV_N + d4 * 4);
        sacc[r] += q4.x * k4.x + q4.y * k4.y + q4.z * k4.z + q4.w * k4.w;
      }
    }

    // ---- online softmax (per row, reduce across lanes = keys) ----
    #pragma unroll
    for (int r = 0; r < 8; ++r) {
      const int i_r = rbase + r;
      const bool valid = (t <= i_r) && (i_r - t <= WIN);
      float sc = valid ? sacc[r] * SCALE : -3.0e38f;
      float mx = sc;
      #pragma unroll
      for (int off = 32; off; off >>= 1) mx = fmaxf(mx, __shfl_xor(mx, off));
      const float m_new = fmaxf(m_run[r], mx);
      const float resc = __expf(m_run[r] - m_new);   // 1 if both -inf
      float pr = valid ? __expf(sc - m_new) : 0.0f;
      float ps = pr;
      #pragma unroll
      for (int off = 32; off; off >>= 1) ps += __shfl_xor(ps, off);
      l_run[r] = l_run[r] * resc + ps;
      m_run[r] = m_new;
      #pragma unroll
      for (int j = 0; j < 4; ++j) out[r][j] *= resc;
      p_lds[wave][r][lane] = pr;    // wave-private: no barrier needed
    }

    // ---- PV: lanes over d (lane owns d = 4*lane..4*lane+3) ----
    #pragma unroll 1
    for (int t4 = 0; t4 < 16; ++t4) {
      float pv[8][4];
      #pragma unroll
      for (int r = 0; r < 8; ++r)
        *(float4*)pv[r] = *(const float4*)(&p_lds[wave][r][t4 * 4]);
      #pragma unroll
      for (int tt = 0; tt < 4; ++tt) {
        int tv = t0 + t4 * 4 + tt;
        if (tv > S_LEN - 1) tv = S_LEN - 1;   // p is 0 there anyway
        const float4 v4 = *(const float4*)(vbase + (size_t)tv * QKV_N + lane * 4);
        #pragma unroll
        for (int r = 0; r < 8; ++r) {
          out[r][0] = fmaf(pv[r][tt], v4.x, out[r][0]);
          out[r][1] = fmaf(pv[r][tt], v4.y, out[r][1]);
          out[r][2] = fmaf(pv[r][tt], v4.z, out[r][2]);
          out[r][3] = fmaf(pv[r][tt], v4.w, out[r][3]);
        }
      }
    }
  }

  #pragma unroll
  for (int r = 0; r < 8; ++r) {
    const float inv = 1.0f / l_run[r];
    float4 o = make_float4(out[r][0] * inv, out[r][1] * inv,
                           out[r][2] * inv, out[r][3] * inv);
    *(float4*)(attn_out + (size_t)(rbase + r) * ATT_N + head * 256 + lane * 4) = o;
  }
}

extern "C" void kernel_launch(void* const* d_in, const int* in_sizes, int n_in,
                              void* d_out, int out_size, void* d_ws, size_t ws_size,
                              hipStream_t stream) {
  const float* hs    = (const float*)d_in[0];   // (2048, 2560)
  const float* cosp  = (const float*)d_in[1];   // (2048, 256)
  const float* sinp  = (const float*)d_in[2];   // (2048, 256)
  const float* w_qkv = (const float*)d_in[3];   // (2560, 4096)
  const float* w_o   = (const float*)d_in[4];   // (2048, 2560)
  const float* qw    = (const float*)d_in[5];   // (256,)
  const float* kw    = (const float*)d_in[6];   // (256,)
  float* out = (float*)d_out;                   // (2048, 2560)

  float* qkv  = (float*)d_ws;                       // 2048*4096 f32 = 32 MiB
  float* attn = qkv + (size_t)S_LEN * QKV_N;        // 2048*2048 f32 = 16 MiB

  // 1) qkv = hs @ w_qkv
  gemm_f32<<<dim3(QKV_N / 128, S_LEN / 128), 256, 0, stream>>>(
      hs, w_qkv, qkv, S_LEN, QKV_N, HID);

  // 2) RMSNorm + RoPE on q,k heads (in place)
  qk_norm_rope<<<(S_LEN * 12) / 4, 256, 0, stream>>>(qkv, cosp, sinp, qw, kw);

  // 3) sliding-window GQA attention
  attn_fwd<<<dim3(S_LEN / 32, NHQ), 256, 0, stream>>>(qkv, attn);

  // 4) out = attn @ w_o
  gemm_f32<<<dim3(HID / 128, S_LEN / 128), 256, 0, stream>>>(
      attn, w_o, out, S_LEN, HID, ATT_N);
}

// Round 3
// 1083.281 us; speedup vs baseline: 1.4818x; 1.4818x over previous
//
#include <hip/hip_runtime.h>
#include <hip/hip_bf16.h>
#include <cstdint>
#include <cstddef>

#define S_LEN 2048
#define HID   2560
#define NHQ   8
#define QKV_N 4096   // (NH + 2*NKV) * D
#define ATT_N 2048   // NH * D
#define WIN   1023
#define SCALE 0.0625f

typedef __attribute__((ext_vector_type(8))) short bf16x8;
typedef __attribute__((ext_vector_type(4))) float f32x4;

__device__ __forceinline__ unsigned bf_hi(float f) {
  unsigned u = __builtin_bit_cast(unsigned, f);
  return (u + 0x7FFFu + ((u >> 16) & 1u)) >> 16;   // RNE bf16 bits in low 16
}
__device__ __forceinline__ float bf_to_f(unsigned h) {
  return __builtin_bit_cast(float, h << 16);
}

// ---------- split+transpose: W[K][N] f32 -> Th/Tl[N][K] bf16 (hi/lo) ----------
__global__ __launch_bounds__(256) void split_transpose(const float* __restrict__ W,
                                                       unsigned short* __restrict__ Th,
                                                       unsigned short* __restrict__ Tl,
                                                       int K, int N) {
  __shared__ float tile[32][33];
  const int tid = threadIdx.x;
  const int kt = blockIdx.y * 32, nt = blockIdx.x * 32;
  {
    const int r = tid >> 3, c = (tid & 7) * 4;
    const float4 v = *(const float4*)(W + (size_t)(kt + r) * N + nt + c);
    tile[r][c] = v.x; tile[r][c + 1] = v.y; tile[r][c + 2] = v.z; tile[r][c + 3] = v.w;
  }
  __syncthreads();
  const int nl = tid >> 3, k = (tid & 7) * 4;
  unsigned hw[2], lw[2];
  #pragma unroll
  for (int j = 0; j < 2; ++j) {
    const float f0 = tile[k + 2 * j][nl], f1 = tile[k + 2 * j + 1][nl];
    const unsigned h0 = bf_hi(f0), h1 = bf_hi(f1);
    const float r0 = f0 - bf_to_f(h0), r1 = f1 - bf_to_f(h1);
    hw[j] = h0 | (h1 << 16);
    lw[j] = bf_hi(r0) | (bf_hi(r1) << 16);
  }
  *(uint2*)(Th + (size_t)(nt + nl) * K + kt + k) = make_uint2(hw[0], hw[1]);
  *(uint2*)(Tl + (size_t)(nt + nl) * K + kt + k) = make_uint2(lw[0], lw[1]);
}

// ---------- split-bf16 MFMA GEMM: C[M][N] f32 = A[M][K] f32 @ BT[N][K] ----------
// 128x128x32 tile, 256 thr = 4 waves (2x2 of 64x64), 4x4 16x16x32 frags/wave.
__global__ __launch_bounds__(256) void gemm_split(const float* __restrict__ A,
                                                  const unsigned short* __restrict__ BTh,
                                                  const unsigned short* __restrict__ BTl,
                                                  float* __restrict__ C,
                                                  int M, int N, int K, int nbx) {
  __shared__ __align__(16) unsigned short As_h[128][40];
  __shared__ __align__(16) unsigned short As_l[128][40];
  __shared__ __align__(16) unsigned short Bs_h[128][40];
  __shared__ __align__(16) unsigned short Bs_l[128][40];

  const int tid = threadIdx.x;
  int bid = blockIdx.x;
  const int cpx = gridDim.x >> 3;                 // grid % 8 == 0 for all calls
  bid = (bid & 7) * cpx + (bid >> 3);             // XCD-contiguous swizzle
  const int bm = (bid / nbx) * 128;
  const int bn = (bid % nbx) * 128;

  const int lane = tid & 63;
  const int wv = tid >> 6;
  const int wr = (wv >> 1) * 64;
  const int wc = (wv & 1) * 64;
  const int frow = lane & 15;
  const int kl = (lane >> 4) * 8;

  const int srow = tid >> 1;              // 0..127
  const int sseg = (tid & 1) * 16;        // k-half within BK=32

  f32x4 acc[4][4] = {};

  const float* aptr = A + (size_t)(bm + srow) * K + sseg;
  const unsigned short* bhp = BTh + (size_t)(bn + srow) * K + sseg;
  const unsigned short* blp = BTl + (size_t)(bn + srow) * K + sseg;

  for (int k0 = 0; k0 < K; k0 += 32) {
    float4 fa[4];
    #pragma unroll
    for (int j = 0; j < 4; ++j) fa[j] = *(const float4*)(aptr + k0 + j * 4);
    const uint4 bh0 = *(const uint4*)(bhp + k0);
    const uint4 bh1 = *(const uint4*)(bhp + k0 + 8);
    const uint4 bl0 = *(const uint4*)(blp + k0);
    const uint4 bl1 = *(const uint4*)(blp + k0 + 8);

    __syncthreads();   // previous iteration's fragment reads done

    unsigned hw[8], lw[8];
    #pragma unroll
    for (int j = 0; j < 4; ++j) {
      const float f[4] = {fa[j].x, fa[j].y, fa[j].z, fa[j].w};
      #pragma unroll
      for (int p = 0; p < 2; ++p) {
        const float f0 = f[2 * p], f1 = f[2 * p + 1];
        const unsigned h0 = bf_hi(f0), h1 = bf_hi(f1);
        const float r0 = f0 - bf_to_f(h0), r1 = f1 - bf_to_f(h1);
        hw[j * 2 + p] = h0 | (h1 << 16);
        lw[j * 2 + p] = bf_hi(r0) | (bf_hi(r1) << 16);
      }
    }
    *(uint4*)&As_h[srow][sseg]     = make_uint4(hw[0], hw[1], hw[2], hw[3]);
    *(uint4*)&As_h[srow][sseg + 8] = make_uint4(hw[4], hw[5], hw[6], hw[7]);
    *(uint4*)&As_l[srow][sseg]     = make_uint4(lw[0], lw[1], lw[2], lw[3]);
    *(uint4*)&As_l[srow][sseg + 8] = make_uint4(lw[4], lw[5], lw[6], lw[7]);
    *(uint4*)&Bs_h[srow][sseg]     = bh0;
    *(uint4*)&Bs_h[srow][sseg + 8] = bh1;
    *(uint4*)&Bs_l[srow][sseg]     = bl0;
    *(uint4*)&Bs_l[srow][sseg + 8] = bl1;
    __syncthreads();

    bf16x8 ah[4], al[4], bhf[4], blf[4];
    #pragma unroll
    for (int i = 0; i < 4; ++i) {
      ah[i]  = *(const bf16x8*)&As_h[wr + i * 16 + frow][kl];
      al[i]  = *(const bf16x8*)&As_l[wr + i * 16 + frow][kl];
      bhf[i] = *(const bf16x8*)&Bs_h[wc + i * 16 + frow][kl];
      blf[i] = *(const bf16x8*)&Bs_l[wc + i * 16 + frow][kl];
    }
    #pragma unroll
    for (int i = 0; i < 4; ++i)
      #pragma unroll
      for (int j = 0; j < 4; ++j) {
        acc[i][j] = __builtin_amdgcn_mfma_f32_16x16x32_bf16(ah[i], bhf[j], acc[i][j], 0, 0, 0);
        acc[i][j] = __builtin_amdgcn_mfma_f32_16x16x32_bf16(ah[i], blf[j], acc[i][j], 0, 0, 0);
        acc[i][j] = __builtin_amdgcn_mfma_f32_16x16x32_bf16(al[i], bhf[j], acc[i][j], 0, 0, 0);
      }
  }

  #pragma unroll
  for (int i = 0; i < 4; ++i) {
    const int r0 = bm + wr + i * 16 + (lane >> 4) * 4;
    #pragma unroll
    for (int j = 0; j < 4; ++j) {
      const int c = bn + wc + j * 16 + frow;
      #pragma unroll
      for (int r = 0; r < 4; ++r)
        C[(size_t)(r0 + r) * N + c] = acc[i][j][r];
    }
  }
}

// ---------- fp32 fallback GEMM (proven path, used only if ws is small) ----------
__global__ __launch_bounds__(256) void gemm_f32(const float* __restrict__ A,
                                                const float* __restrict__ B,
                                                float* __restrict__ C,
                                                int M, int N, int K) {
  __shared__ float As[16][132];
  __shared__ float Bs[16][128];
  const int tid = threadIdx.x;
  const int tx  = tid & 15;
  const int ty  = tid >> 4;
  const int bm  = blockIdx.y * 128;
  const int bn  = blockIdx.x * 128;

  const int arow = tid >> 2;
  const int acol = (tid & 3) << 2;
  const int brow = tid >> 5;
  const int bcol = (tid & 31) << 2;

  float acc[2][2][4][4] = {};

  for (int k0 = 0; k0 < K; k0 += 16) {
    float4 a0 = *(const float4*)(A + (size_t)(bm + arow)      * K + k0 + acol);
    float4 a1 = *(const float4*)(A + (size_t)(bm + arow + 64) * K + k0 + acol);
    float4 b0 = *(const float4*)(B + (size_t)(k0 + brow)     * N + bn + bcol);
    float4 b1 = *(const float4*)(B + (size_t)(k0 + brow + 8) * N + bn + bcol);
    As[acol + 0][arow] = a0.x; As[acol + 1][arow] = a0.y;
    As[acol + 2][arow] = a0.z; As[acol + 3][arow] = a0.w;
    As[acol + 0][arow + 64] = a1.x; As[acol + 1][arow + 64] = a1.y;
    As[acol + 2][arow + 64] = a1.z; As[acol + 3][arow + 64] = a1.w;
    *(float4*)(&Bs[brow][bcol])     = b0;
    *(float4*)(&Bs[brow + 8][bcol]) = b1;
    __syncthreads();
    #pragma unroll
    for (int kk = 0; kk < 16; ++kk) {
      float av[2][4], bv[2][4];
      *(float4*)av[0] = *(const float4*)(&As[kk][ty * 4]);
      *(float4*)av[1] = *(const float4*)(&As[kk][ty * 4 + 64]);
      *(float4*)bv[0] = *(const float4*)(&Bs[kk][tx * 4]);
      *(float4*)bv[1] = *(const float4*)(&Bs[kk][tx * 4 + 64]);
      #pragma unroll
      for (int i = 0; i < 2; ++i)
        #pragma unroll
        for (int p = 0; p < 4; ++p)
          #pragma unroll
          for (int j = 0; j < 2; ++j)
            #pragma unroll
            for (int q = 0; q < 4; ++q)
              acc[i][j][p][q] = fmaf(av[i][p], bv[j][q], acc[i][j][p][q]);
    }
    __syncthreads();
  }
  #pragma unroll
  for (int i = 0; i < 2; ++i)
    #pragma unroll
    for (int p = 0; p < 4; ++p) {
      const size_t row = (size_t)(bm + ty * 4 + i * 64 + p);
      #pragma unroll
      for (int j = 0; j < 2; ++j) {
        float4 o = make_float4(acc[i][j][p][0], acc[i][j][p][1],
                               acc[i][j][p][2], acc[i][j][p][3]);
        *(float4*)(C + row * N + bn + tx * 4 + j * 64) = o;
      }
    }
}

// ---------------- fused per-head RMSNorm + RoPE, in-place on qkv ----------------
__global__ __launch_bounds__(256) void qk_norm_rope(float* __restrict__ qkv,
                                                    const float* __restrict__ cosp,
                                                    const float* __restrict__ sinp,
                                                    const float* __restrict__ qw,
                                                    const float* __restrict__ kw) {
  const int lane = threadIdx.x & 63;
  const int wave = threadIdx.x >> 6;
  const int row  = blockIdx.x * 4 + wave;
  const int s    = row / 12;
  const int c    = row % 12;
  float* p = qkv + (size_t)s * QKV_N + c * 256;

  float4 x = *(const float4*)(p + lane * 4);
  float ss = x.x * x.x + x.y * x.y + x.z * x.z + x.w * x.w;
  #pragma unroll
  for (int off = 32; off; off >>= 1) ss += __shfl_xor(ss, off);
  const float scale = rsqrtf(ss * (1.0f / 256.0f) + 1e-6f);

  const float* wp = (c < 8) ? qw : kw;
  float4 w4 = *(const float4*)(wp + lane * 4);
  float y0 = x.x * scale * (1.0f + w4.x);
  float y1 = x.y * scale * (1.0f + w4.y);
  float y2 = x.z * scale * (1.0f + w4.z);
  float y3 = x.w * scale * (1.0f + w4.w);

  float z0 = __shfl_xor(y0, 32);
  float z1 = __shfl_xor(y1, 32);
  float z2 = __shfl_xor(y2, 32);
  float z3 = __shfl_xor(y3, 32);
  const float sgn = (lane < 32) ? -1.0f : 1.0f;

  float4 c4 = *(const float4*)(cosp + (size_t)s * 256 + lane * 4);
  float4 s4 = *(const float4*)(sinp + (size_t)s * 256 + lane * 4);
  float4 o;
  o.x = y0 * c4.x + sgn * z0 * s4.x;
  o.y = y1 * c4.y + sgn * z1 * s4.y;
  o.z = y2 * c4.z + sgn * z2 * s4.z;
  o.w = y3 * c4.w + sgn * z3 * s4.w;
  *(float4*)(p + lane * 4) = o;
}

// ---------------- sliding-window GQA flash attention (fp32), 4 rows/wave ----------------
__global__ __launch_bounds__(256) void attn_fwd(const float* __restrict__ qkv,
                                                float* __restrict__ attn_out) {
  __shared__ float p_lds[4][4][64];
  const int lane = threadIdx.x & 63;
  const int wave = __builtin_amdgcn_readfirstlane(threadIdx.x >> 6);
  const int head = blockIdx.y;
  const int kvh  = head >> 1;
  const int rbase = blockIdx.x * 16 + wave * 4;

  const float* kbase = qkv + 2048 + kvh * 256;
  const float* vbase = qkv + 3072 + kvh * 256;
  const float* qbase = qkv + head * 256;

  float out[4][4] = {};
  float m_run[4], l_run[4];
  #pragma unroll
  for (int r = 0; r < 4; ++r) { m_run[r] = -3.0e38f; l_run[r] = 0.0f; }

  const int t_hi = rbase + 3;
  const int t_lo_raw = rbase - WIN;
  int t0 = (t_lo_raw < 0) ? 0 : (t_lo_raw & ~63);

  for (; t0 <= t_hi; t0 += 64) {
    const int t = t0 + lane;
    const int t_load = (t > S_LEN - 1) ? (S_LEN - 1) : t;

    float sacc[4] = {};
    const float* krow = kbase + (size_t)t_load * QKV_N;
    #pragma unroll 4
    for (int d4 = 0; d4 < 64; ++d4) {
      const float4 k4 = *(const float4*)(krow + d4 * 4);
      #pragma unroll
      for (int r = 0; r < 4; ++r) {
        const float4 q4 = *(const float4*)(qbase + (size_t)(rbase + r) * QKV_N + d4 * 4);
        sacc[r] += q4.x * k4.x + q4.y * k4.y + q4.z * k4.z + q4.w * k4.w;
      }
    }

    #pragma unroll
    for (int r = 0; r < 4; ++r) {
      const int i_r = rbase + r;
      const bool valid = (t <= i_r) && (i_r - t <= WIN);
      float sc = valid ? sacc[r] * SCALE : -3.0e38f;
      float mx = sc;
      #pragma unroll
      for (int off = 32; off; off >>= 1) mx = fmaxf(mx, __shfl_xor(mx, off));
      const float m_new = fmaxf(m_run[r], mx);
      const float resc = __expf(m_run[r] - m_new);
      float pr = valid ? __expf(sc - m_new) : 0.0f;
      float ps = pr;
      #pragma unroll
      for (int off = 32; off; off >>= 1) ps += __shfl_xor(ps, off);
      l_run[r] = l_run[r] * resc + ps;
      m_run[r] = m_new;
      #pragma unroll
      for (int j = 0; j < 4; ++j) out[r][j] *= resc;
      p_lds[wave][r][lane] = pr;
    }

    #pragma unroll 1
    for (int t4 = 0; t4 < 16; ++t4) {
      float pv[4][4];
      #pragma unroll
      for (int r = 0; r < 4; ++r)
        *(float4*)pv[r] = *(const float4*)(&p_lds[wave][r][t4 * 4]);
      #pragma unroll
      for (int tt = 0; tt < 4; ++tt) {
        int tv = t0 + t4 * 4 + tt;
        if (tv > S_LEN - 1) tv = S_LEN - 1;
        const float4 v4 = *(const float4*)(vbase + (size_t)tv * QKV_N + lane * 4);
        #pragma unroll
        for (int r = 0; r < 4; ++r) {
          out[r][0] = fmaf(pv[r][tt], v4.x, out[r][0]);
          out[r][1] = fmaf(pv[r][tt], v4.y, out[r][1]);
          out[r][2] = fmaf(pv[r][tt], v4.z, out[r][2]);
          out[r][3] = fmaf(pv[r][tt], v4.w, out[r][3]);
        }
      }
    }
  }

  #pragma unroll
  for (int r = 0; r < 4; ++r) {
    const float inv = 1.0f / l_run[r];
    float4 o = make_float4(out[r][0] * inv, out[r][1] * inv,
                           out[r][2] * inv, out[r][3] * inv);
    *(float4*)(attn_out + (size_t)(rbase + r) * ATT_N + head * 256 + lane * 4) = o;
  }
}

extern "C" void kernel_launch(void* const* d_in, const int* in_sizes, int n_in,
                              void* d_out, int out_size, void* d_ws, size_t ws_size,
                              hipStream_t stream) {
  const float* hs    = (const float*)d_in[0];
  const float* cosp  = (const float*)d_in[1];
  const float* sinp  = (const float*)d_in[2];
  const float* w_qkv = (const float*)d_in[3];   // (2560, 4096)
  const float* w_o   = (const float*)d_in[4];   // (2048, 2560)
  const float* qw    = (const float*)d_in[5];
  const float* kw    = (const float*)d_in[6];
  float* out = (float*)d_out;

  const size_t MB = 1024 * 1024;
  char* ws = (char*)d_ws;

  if (ws_size >= 72 * MB) {
    // --- split-bf16 MFMA path; liveness-overlaid workspace, peak 72 MiB ---
    float* qkv = (float*)ws;                              // [0,32M) alive steps 2-4
    unsigned short* wh = (unsigned short*)(ws + 32 * MB); // [32,52M) dead after gemm1
    unsigned short* wl = (unsigned short*)(ws + 52 * MB); // [52,72M) dead after gemm1
    float* attn = (float*)(ws + 32 * MB);                 // [32,48M) alive steps 4-6
    unsigned short* oh = (unsigned short*)(ws + 48 * MB); // [48,58M)
    unsigned short* ol = (unsigned short*)(ws + 58 * MB); // [58,68M)

    split_transpose<<<dim3(QKV_N / 32, HID / 32), 256, 0, stream>>>(
        w_qkv, wh, wl, HID, QKV_N);
    gemm_split<<<(S_LEN / 128) * (QKV_N / 128), 256, 0, stream>>>(
        hs, wh, wl, qkv, S_LEN, QKV_N, HID, QKV_N / 128);
    qk_norm_rope<<<(S_LEN * 12) / 4, 256, 0, stream>>>(qkv, cosp, sinp, qw, kw);
    attn_fwd<<<dim3(S_LEN / 16, NHQ), 256, 0, stream>>>(qkv, attn);
    split_transpose<<<dim3(HID / 32, ATT_N / 32), 256, 0, stream>>>(
        w_o, oh, ol, ATT_N, HID);
    gemm_split<<<(S_LEN / 128) * (HID / 128), 256, 0, stream>>>(
        attn, oh, ol, out, S_LEN, HID, ATT_N, HID / 128);
  } else {
    // --- proven fp32 path (48 MiB) ---
    float* qkv  = (float*)ws;
    float* attn = qkv + (size_t)S_LEN * QKV_N;

    gemm_f32<<<dim3(QKV_N / 128, S_LEN / 128), 256, 0, stream>>>(
        hs, w_qkv, qkv, S_LEN, QKV_N, HID);
    qk_norm_rope<<<(S_LEN * 12) / 4, 256, 0, stream>>>(qkv, cosp, sinp, qw, kw);
    attn_fwd<<<dim3(S_LEN / 16, NHQ), 256, 0, stream>>>(qkv, attn);
    gemm_f32<<<dim3(HID / 128, S_LEN / 128), 256, 0, stream>>>(
        attn, w_o, out, S_LEN, HID, ATT_N);
  }
}

// Round 4
// 569.196 us; speedup vs baseline: 2.8202x; 1.9032x over previous
//
#include <hip/hip_runtime.h>
#include <hip/hip_bf16.h>
#include <cstdint>
#include <cstddef>

#define S_LEN 2048
#define HID   2560
#define NHQ   8
#define QKV_N 4096   // (NH + 2*NKV) * D
#define ATT_N 2048   // NH * D
#define WIN   1023
#define SCALE 0.0625f
#define NINF  -3.0e38f

typedef __attribute__((ext_vector_type(8))) short bf16x8;
typedef __attribute__((ext_vector_type(4))) float f32x4;

__device__ __forceinline__ unsigned bf_hi(float f) {
  unsigned u = __builtin_bit_cast(unsigned, f);
  return (u + 0x7FFFu + ((u >> 16) & 1u)) >> 16;   // RNE bf16 bits
}
__device__ __forceinline__ float bf_to_f(unsigned h) {
  return __builtin_bit_cast(float, h << 16);
}
__device__ __forceinline__ void g2l16(const void* g, void* l) {
  __builtin_amdgcn_global_load_lds((const __attribute__((address_space(1))) void*)g,
                                   (__attribute__((address_space(3))) void*)l,
                                   16, 0, 0);
}

// ---------- split+transpose: W[K][N] f32 -> Th/Tl[N][K] bf16 (hi/lo) ----------
__global__ __launch_bounds__(256) void split_transpose(const float* __restrict__ W,
                                                       unsigned short* __restrict__ Th,
                                                       unsigned short* __restrict__ Tl,
                                                       int K, int N) {
  __shared__ float tile[32][33];
  const int tid = threadIdx.x;
  const int kt = blockIdx.y * 32, nt = blockIdx.x * 32;
  {
    const int r = tid >> 3, c = (tid & 7) * 4;
    const float4 v = *(const float4*)(W + (size_t)(kt + r) * N + nt + c);
    tile[r][c] = v.x; tile[r][c + 1] = v.y; tile[r][c + 2] = v.z; tile[r][c + 3] = v.w;
  }
  __syncthreads();
  const int nl = tid >> 3, k = (tid & 7) * 4;
  unsigned hw[2], lw[2];
  #pragma unroll
  for (int j = 0; j < 2; ++j) {
    const float f0 = tile[k + 2 * j][nl], f1 = tile[k + 2 * j + 1][nl];
    const unsigned h0 = bf_hi(f0), h1 = bf_hi(f1);
    const float r0 = f0 - bf_to_f(h0), r1 = f1 - bf_to_f(h1);
    hw[j] = h0 | (h1 << 16);
    lw[j] = bf_hi(r0) | (bf_hi(r1) << 16);
  }
  *(uint2*)(Th + (size_t)(nt + nl) * K + kt + k) = make_uint2(hw[0], hw[1]);
  *(uint2*)(Tl + (size_t)(nt + nl) * K + kt + k) = make_uint2(lw[0], lw[1]);
}

// ---------- split-bf16 MFMA GEMM (proven round-3 kernel, unchanged) ----------
__global__ __launch_bounds__(256) void gemm_split(const float* __restrict__ A,
                                                  const unsigned short* __restrict__ BTh,
                                                  const unsigned short* __restrict__ BTl,
                                                  float* __restrict__ C,
                                                  int M, int N, int K, int nbx) {
  __shared__ __align__(16) unsigned short As_h[128][40];
  __shared__ __align__(16) unsigned short As_l[128][40];
  __shared__ __align__(16) unsigned short Bs_h[128][40];
  __shared__ __align__(16) unsigned short Bs_l[128][40];

  const int tid = threadIdx.x;
  int bid = blockIdx.x;
  const int cpx = gridDim.x >> 3;
  bid = (bid & 7) * cpx + (bid >> 3);
  const int bm = (bid / nbx) * 128;
  const int bn = (bid % nbx) * 128;

  const int lane = tid & 63;
  const int wv = tid >> 6;
  const int wr = (wv >> 1) * 64;
  const int wc = (wv & 1) * 64;
  const int frow = lane & 15;
  const int kl = (lane >> 4) * 8;

  const int srow = tid >> 1;
  const int sseg = (tid & 1) * 16;

  f32x4 acc[4][4] = {};

  const float* aptr = A + (size_t)(bm + srow) * K + sseg;
  const unsigned short* bhp = BTh + (size_t)(bn + srow) * K + sseg;
  const unsigned short* blp = BTl + (size_t)(bn + srow) * K + sseg;

  for (int k0 = 0; k0 < K; k0 += 32) {
    float4 fa[4];
    #pragma unroll
    for (int j = 0; j < 4; ++j) fa[j] = *(const float4*)(aptr + k0 + j * 4);
    const uint4 bh0 = *(const uint4*)(bhp + k0);
    const uint4 bh1 = *(const uint4*)(bhp + k0 + 8);
    const uint4 bl0 = *(const uint4*)(blp + k0);
    const uint4 bl1 = *(const uint4*)(blp + k0 + 8);

    __syncthreads();

    unsigned hw[8], lw[8];
    #pragma unroll
    for (int j = 0; j < 4; ++j) {
      const float f[4] = {fa[j].x, fa[j].y, fa[j].z, fa[j].w};
      #pragma unroll
      for (int p = 0; p < 2; ++p) {
        const float f0 = f[2 * p], f1 = f[2 * p + 1];
        const unsigned h0 = bf_hi(f0), h1 = bf_hi(f1);
        const float r0 = f0 - bf_to_f(h0), r1 = f1 - bf_to_f(h1);
        hw[j * 2 + p] = h0 | (h1 << 16);
        lw[j * 2 + p] = bf_hi(r0) | (bf_hi(r1) << 16);
      }
    }
    *(uint4*)&As_h[srow][sseg]     = make_uint4(hw[0], hw[1], hw[2], hw[3]);
    *(uint4*)&As_h[srow][sseg + 8] = make_uint4(hw[4], hw[5], hw[6], hw[7]);
    *(uint4*)&As_l[srow][sseg]     = make_uint4(lw[0], lw[1], lw[2], lw[3]);
    *(uint4*)&As_l[srow][sseg + 8] = make_uint4(lw[4], lw[5], lw[6], lw[7]);
    *(uint4*)&Bs_h[srow][sseg]     = bh0;
    *(uint4*)&Bs_h[srow][sseg + 8] = bh1;
    *(uint4*)&Bs_l[srow][sseg]     = bl0;
    *(uint4*)&Bs_l[srow][sseg + 8] = bl1;
    __syncthreads();

    bf16x8 ah[4], al[4], bhf[4], blf[4];
    #pragma unroll
    for (int i = 0; i < 4; ++i) {
      ah[i]  = *(const bf16x8*)&As_h[wr + i * 16 + frow][kl];
      al[i]  = *(const bf16x8*)&As_l[wr + i * 16 + frow][kl];
      bhf[i] = *(const bf16x8*)&Bs_h[wc + i * 16 + frow][kl];
      blf[i] = *(const bf16x8*)&Bs_l[wc + i * 16 + frow][kl];
    }
    #pragma unroll
    for (int i = 0; i < 4; ++i)
      #pragma unroll
      for (int j = 0; j < 4; ++j) {
        acc[i][j] = __builtin_amdgcn_mfma_f32_16x16x32_bf16(ah[i], bhf[j], acc[i][j], 0, 0, 0);
        acc[i][j] = __builtin_amdgcn_mfma_f32_16x16x32_bf16(ah[i], blf[j], acc[i][j], 0, 0, 0);
        acc[i][j] = __builtin_amdgcn_mfma_f32_16x16x32_bf16(al[i], bhf[j], acc[i][j], 0, 0, 0);
      }
  }

  #pragma unroll
  for (int i = 0; i < 4; ++i) {
    const int r0 = bm + wr + i * 16 + (lane >> 4) * 4;
    #pragma unroll
    for (int j = 0; j < 4; ++j) {
      const int c = bn + wc + j * 16 + frow;
      #pragma unroll
      for (int r = 0; r < 4; ++r)
        C[(size_t)(r0 + r) * N + c] = acc[i][j][r];
    }
  }
}

// ------- RMSNorm + RoPE -> split-bf16 Q (scaled) / K buffers, MFMA layout -------
// One wave per (s, c): c<8 -> Q head c, else K head c-8. Writes hi/lo bf16.
__global__ __launch_bounds__(256) void qk_norm_rope_split(
    const float* __restrict__ qkv, const float* __restrict__ cosp,
    const float* __restrict__ sinp, const float* __restrict__ qw,
    const float* __restrict__ kw,
    unsigned short* __restrict__ Qh, unsigned short* __restrict__ Ql,
    unsigned short* __restrict__ Kh, unsigned short* __restrict__ Kl) {
  const int lane = threadIdx.x & 63;
  const int wave = threadIdx.x >> 6;
  const int row  = blockIdx.x * 4 + wave;
  const int s    = row / 12;
  const int c    = row % 12;
  const float* p = qkv + (size_t)s * QKV_N + c * 256;

  float4 x = *(const float4*)(p + lane * 4);
  float ss = x.x * x.x + x.y * x.y + x.z * x.z + x.w * x.w;
  #pragma unroll
  for (int off = 32; off; off >>= 1) ss += __shfl_xor(ss, off);
  const float scale = rsqrtf(ss * (1.0f / 256.0f) + 1e-6f);

  const float* wp = (c < 8) ? qw : kw;
  float4 w4 = *(const float4*)(wp + lane * 4);
  float y0 = x.x * scale * (1.0f + w4.x);
  float y1 = x.y * scale * (1.0f + w4.y);
  float y2 = x.z * scale * (1.0f + w4.z);
  float y3 = x.w * scale * (1.0f + w4.w);

  float z0 = __shfl_xor(y0, 32);
  float z1 = __shfl_xor(y1, 32);
  float z2 = __shfl_xor(y2, 32);
  float z3 = __shfl_xor(y3, 32);
  const float sgn = (lane < 32) ? -1.0f : 1.0f;

  float4 c4 = *(const float4*)(cosp + (size_t)s * 256 + lane * 4);
  float4 s4 = *(const float4*)(sinp + (size_t)s * 256 + lane * 4);
  float o[4];
  o[0] = y0 * c4.x + sgn * z0 * s4.x;
  o[1] = y1 * c4.y + sgn * z1 * s4.y;
  o[2] = y2 * c4.z + sgn * z2 * s4.z;
  o[3] = y3 * c4.w + sgn * z3 * s4.w;

  const float mul = (c < 8) ? SCALE : 1.0f;   // fold softmax scale into Q
  #pragma unroll
  for (int j = 0; j < 4; ++j) o[j] *= mul;

  unsigned h[4], lo[4];
  #pragma unroll
  for (int j = 0; j < 4; ++j) {
    h[j] = bf_hi(o[j]);
    lo[j] = bf_hi(o[j] - bf_to_f(h[j]));
  }
  const size_t off = ((c < 8) ? ((size_t)c * S_LEN + s)
                              : ((size_t)(c - 8) * S_LEN + s)) * 256 + lane * 4;
  unsigned short* dh = (c < 8 ? Qh : Kh) + off;
  unsigned short* dl = (c < 8 ? Ql : Kl) + off;
  *(uint2*)dh = make_uint2(h[0] | (h[1] << 16), h[2] | (h[3] << 16));
  *(uint2*)dl = make_uint2(lo[0] | (lo[1] << 16), lo[2] | (lo[3] << 16));
}

// ---------- V split + transpose: qkv V region -> VT[kvh][256][2048] hi/lo ----------
__global__ __launch_bounds__(256) void v_split_transpose(
    const float* __restrict__ qkv,
    unsigned short* __restrict__ VTh, unsigned short* __restrict__ VTl) {
  __shared__ float tile[32][33];
  const int tid = threadIdx.x;
  const int s0 = blockIdx.x * 32, d0 = blockIdx.y * 32, kvh = blockIdx.z;
  {
    const int r = tid >> 3, c = (tid & 7) * 4;
    const float4 v = *(const float4*)(qkv + (size_t)(s0 + r) * QKV_N + 3072 + kvh * 256 + d0 + c);
    tile[r][c] = v.x; tile[r][c + 1] = v.y; tile[r][c + 2] = v.z; tile[r][c + 3] = v.w;
  }
  __syncthreads();
  const int dd = tid >> 3, sc = (tid & 7) * 4;
  unsigned h[4], lo[4];
  #pragma unroll
  for (int j = 0; j < 4; ++j) {
    const float f = tile[sc + j][dd];
    h[j] = bf_hi(f);
    lo[j] = bf_hi(f - bf_to_f(h[j]));
  }
  const size_t off = ((size_t)kvh * 256 + d0 + dd) * S_LEN + s0 + sc;
  *(uint2*)(VTh + off) = make_uint2(h[0] | (h[1] << 16), h[2] | (h[3] << 16));
  *(uint2*)(VTl + off) = make_uint2(lo[0] | (lo[1] << 16), lo[2] | (lo[3] << 16));
}

// ---------------- MFMA sliding-window GQA flash attention ----------------
// 2 waves x 16 q-rows per block, grid (S/32, NHQ). KVBLK=32 keys staged in LDS
// via global_load_lds with XOR-swizzled per-lane SOURCE addresses (linear dest).
#define KH_U  0
#define KL_U  8192
#define VTH_U 16384
#define VTL_U 24576
#define PH_U  32768
#define PL_U  34048
__global__ __launch_bounds__(128, 2) void attn_mfma(
    const unsigned short* __restrict__ Qh, const unsigned short* __restrict__ Ql,
    const unsigned short* __restrict__ Kh, const unsigned short* __restrict__ Kl,
    const unsigned short* __restrict__ VTh, const unsigned short* __restrict__ VTl,
    float* __restrict__ attn_out) {
  __shared__ __align__(16) unsigned short smem[35328];   // 70.7 KiB

  const int tid  = threadIdx.x;
  const int lane = tid & 63;
  const int wv   = __builtin_amdgcn_readfirstlane(tid >> 6);
  const int head = blockIdx.y;
  const int kvh  = head >> 1;
  const int q0   = blockIdx.x * 32;
  const int g16  = lane >> 4;      // 0..3
  const int c16  = lane & 15;      // 0..15

  // ---- Q fragments to registers (A-operand layout), hi/lo ----
  const int qrow = q0 + wv * 16 + c16;
  bf16x8 qh[8], ql[8];
  {
    const unsigned short* qph = Qh + ((size_t)head * S_LEN + qrow) * 256 + g16 * 8;
    const unsigned short* qpl = Ql + ((size_t)head * S_LEN + qrow) * 256 + g16 * 8;
    #pragma unroll
    for (int dc = 0; dc < 8; ++dc) {
      qh[dc] = *(const bf16x8*)(qph + dc * 32);
      ql[dc] = *(const bf16x8*)(qpl + dc * 32);
    }
  }

  f32x4 o_acc[16] = {};
  float m_run[4], l_run[4];
  #pragma unroll
  for (int r = 0; r < 4; ++r) { m_run[r] = NINF; l_run[r] = 0.0f; }

  const int rmin = q0 + wv * 16, rmax = rmin + 15;
  const unsigned short* kh_g  = Kh  + (size_t)kvh * S_LEN * 256;
  const unsigned short* kl_g  = Kl  + (size_t)kvh * S_LEN * 256;
  const unsigned short* vth_g = VTh + (size_t)kvh * 256 * S_LEN;
  const unsigned short* vtl_g = VTl + (size_t)kvh * 256 * S_LEN;

  const int kstart = (q0 > WIN) ? ((q0 - WIN) & ~31) : 0;
  const int kend   = q0 + 31;

  for (int t0 = kstart; t0 <= kend; t0 += 32) {
    // ---- stage K (32x256, linear rows, slot^=(row&7)) and VT (256x32, slot^=((d>>1)&3)) ----
    {
      char* lbase = (char*)smem + ((tid & ~63) << 4);   // + i*128*16 per iter
      #pragma unroll
      for (int i = 0; i < 8; ++i) {                      // K hi
        const int uu = i * 128 + tid, row = uu >> 5, sl = uu & 31;
        g2l16(kh_g + (size_t)(t0 + row) * 256 + ((sl ^ (row & 7)) * 8),
              lbase + i * 2048);
      }
      #pragma unroll
      for (int i = 0; i < 8; ++i) {                      // K lo
        const int uu = i * 128 + tid, row = uu >> 5, sl = uu & 31;
        g2l16(kl_g + (size_t)(t0 + row) * 256 + ((sl ^ (row & 7)) * 8),
              lbase + 16384 + i * 2048);
      }
      #pragma unroll
      for (int i = 0; i < 8; ++i) {                      // VT hi
        const int uu = i * 128 + tid, d = uu >> 2, sl = uu & 3;
        g2l16(vth_g + (size_t)d * S_LEN + t0 + ((sl ^ ((d >> 1) & 3)) * 8),
              lbase + 32768 + i * 2048);
      }
      #pragma unroll
      for (int i = 0; i < 8; ++i) {                      // VT lo
        const int uu = i * 128 + tid, d = uu >> 2, sl = uu & 3;
        g2l16(vtl_g + (size_t)d * S_LEN + t0 + ((sl ^ ((d >> 1) & 3)) * 8),
              lbase + 49152 + i * 2048);
      }
    }
    __syncthreads();

    const bool active = (t0 <= rmax) && (t0 + 31 + WIN >= rmin);
    if (active) {
      // ---- QK^T: S[16q x 32k] via 2 key-tiles, split 3-term MFMA ----
      f32x4 sa[2] = {};
      #pragma unroll
      for (int t = 0; t < 2; ++t) {
        const int krow = t * 16 + c16;
        const int swz = krow & 7;
        #pragma unroll
        for (int dc = 0; dc < 8; ++dc) {
          const int sl = ((dc * 4 + g16) ^ swz) * 16;
          const bf16x8 kfh = *(const bf16x8*)((const char*)smem + krow * 512 + sl);
          const bf16x8 kfl = *(const bf16x8*)((const char*)smem + 16384 + krow * 512 + sl);
          sa[t] = __builtin_amdgcn_mfma_f32_16x16x32_bf16(qh[dc], kfh, sa[t], 0, 0, 0);
          sa[t] = __builtin_amdgcn_mfma_f32_16x16x32_bf16(qh[dc], kfl, sa[t], 0, 0, 0);
          sa[t] = __builtin_amdgcn_mfma_f32_16x16x32_bf16(ql[dc], kfh, sa[t], 0, 0, 0);
        }
      }

      // ---- online softmax (rows spread: row=(g16)*4+r, key col=c16+16t) ----
      const int k0c = t0 + c16;
      #pragma unroll
      for (int r = 0; r < 4; ++r) {
        const int q = rmin + g16 * 4 + r;
        const bool v0 = (k0c <= q) && (q - k0c <= WIN);
        const bool v1 = (k0c + 16 <= q) && (q - (k0c + 16) <= WIN);
        float s0 = v0 ? sa[0][r] : NINF;
        float s1 = v1 ? sa[1][r] : NINF;
        float mx = fmaxf(s0, s1);
        #pragma unroll
        for (int off = 8; off; off >>= 1) mx = fmaxf(mx, __shfl_xor(mx, off));
        const float m_new = fmaxf(m_run[r], mx);
        const float rs = __expf(m_run[r] - m_new);
        const float p0 = v0 ? __expf(s0 - m_new) : 0.0f;
        const float p1 = v1 ? __expf(s1 - m_new) : 0.0f;
        float psum = p0 + p1;
        #pragma unroll
        for (int off = 8; off; off >>= 1) psum += __shfl_xor(psum, off);
        l_run[r] = l_run[r] * rs + psum;
        m_run[r] = m_new;
        #pragma unroll
        for (int dt = 0; dt < 16; ++dt) o_acc[dt][r] *= rs;
        // split P -> LDS (row = g16*4+r, cols c16 / 16+c16), stride 40 ush
        const int pro = wv * 640 + (g16 * 4 + r) * 40;
        const unsigned h0 = bf_hi(p0), h1 = bf_hi(p1);
        smem[PH_U + pro + c16]      = (unsigned short)h0;
        smem[PH_U + pro + 16 + c16] = (unsigned short)h1;
        smem[PL_U + pro + c16]      = (unsigned short)bf_hi(p0 - bf_to_f(h0));
        smem[PL_U + pro + 16 + c16] = (unsigned short)bf_hi(p1 - bf_to_f(h1));
      }

      // ---- PV: O[16q x 256d] += P[16x32] @ V[32x16] per d-tile ----
      const bf16x8 pah = *(const bf16x8*)&smem[PH_U + wv * 640 + c16 * 40 + g16 * 8];
      const bf16x8 pal = *(const bf16x8*)&smem[PL_U + wv * 640 + c16 * 40 + g16 * 8];
      #pragma unroll
      for (int dt = 0; dt < 16; ++dt) {
        const int vrow = dt * 16 + c16;
        const int sl = (g16 ^ ((vrow >> 1) & 3)) * 16;
        const bf16x8 vfh = *(const bf16x8*)((const char*)smem + 32768 + vrow * 64 + sl);
        const bf16x8 vfl = *(const bf16x8*)((const char*)smem + 49152 + vrow * 64 + sl);
        o_acc[dt] = __builtin_amdgcn_mfma_f32_16x16x32_bf16(pah, vfh, o_acc[dt], 0, 0, 0);
        o_acc[dt] = __builtin_amdgcn_mfma_f32_16x16x32_bf16(pah, vfl, o_acc[dt], 0, 0, 0);
        o_acc[dt] = __builtin_amdgcn_mfma_f32_16x16x32_bf16(pal, vfh, o_acc[dt], 0, 0, 0);
      }
    }
    __syncthreads();
  }

  // ---- epilogue ----
  #pragma unroll
  for (int r = 0; r < 4; ++r) {
    const float inv = 1.0f / l_run[r];
    float* orow = attn_out + (size_t)(rmin + g16 * 4 + r) * ATT_N + head * 256 + c16;
    #pragma unroll
    for (int dt = 0; dt < 16; ++dt) orow[dt * 16] = o_acc[dt][r] * inv;
  }
}

extern "C" void kernel_launch(void* const* d_in, const int* in_sizes, int n_in,
                              void* d_out, int out_size, void* d_ws, size_t ws_size,
                              hipStream_t stream) {
  const float* hs    = (const float*)d_in[0];
  const float* cosp  = (const float*)d_in[1];
  const float* sinp  = (const float*)d_in[2];
  const float* w_qkv = (const float*)d_in[3];   // (2560, 4096)
  const float* w_o   = (const float*)d_in[4];   // (2048, 2560)
  const float* qw    = (const float*)d_in[5];
  const float* kw    = (const float*)d_in[6];
  float* out = (float*)d_out;

  const size_t MB = 1024 * 1024;
  char* ws = (char*)d_ws;
  // liveness-overlaid map, peak 72 MiB:
  float* qkv = (float*)ws;                               // [0,32M): gemm1 out, dead after preps
  unsigned short* wh = (unsigned short*)(ws + 32 * MB);  // [32,52M): w_qkv hi, dead after gemm1
  unsigned short* wl = (unsigned short*)(ws + 52 * MB);  // [52,72M): w_qkv lo
  unsigned short* Qh = (unsigned short*)(ws + 32 * MB);  // [32,40M)
  unsigned short* Ql = (unsigned short*)(ws + 40 * MB);  // [40,48M)
  unsigned short* Kh = (unsigned short*)(ws + 48 * MB);  // [48,52M)
  unsigned short* Kl = (unsigned short*)(ws + 52 * MB);  // [52,56M)
  unsigned short* VTh = (unsigned short*)(ws + 56 * MB); // [56,60M)
  unsigned short* VTl = (unsigned short*)(ws + 60 * MB); // [60,64M)
  float* attn = (float*)ws;                              // [0,16M): qkv dead by then
  unsigned short* oh = (unsigned short*)(ws + 16 * MB);  // [16,26M)
  unsigned short* ol = (unsigned short*)(ws + 26 * MB);  // [26,36M)

  // 1) w_qkv -> split^T
  split_transpose<<<dim3(QKV_N / 32, HID / 32), 256, 0, stream>>>(
      w_qkv, wh, wl, HID, QKV_N);
  // 2) qkv = hs @ w_qkv
  gemm_split<<<(S_LEN / 128) * (QKV_N / 128), 256, 0, stream>>>(
      hs, wh, wl, qkv, S_LEN, QKV_N, HID, QKV_N / 128);
  // 3) norm+rope -> Q/K split bf16 (MFMA layout, SCALE folded into Q)
  qk_norm_rope_split<<<(S_LEN * 12) / 4, 256, 0, stream>>>(
      qkv, cosp, sinp, qw, kw, Qh, Ql, Kh, Kl);
  // 4) V -> split + transpose
  v_split_transpose<<<dim3(S_LEN / 32, 256 / 32, 4), 256, 0, stream>>>(
      qkv, VTh, VTl);
  // 5) MFMA flash attention
  attn_mfma<<<dim3(S_LEN / 32, NHQ), 128, 0, stream>>>(
      Qh, Ql, Kh, Kl, VTh, VTl, attn);
  // 6) w_o -> split^T
  split_transpose<<<dim3(HID / 32, ATT_N / 32), 256, 0, stream>>>(
      w_o, oh, ol, ATT_N, HID);
  // 7) out = attn @ w_o
  gemm_split<<<(S_LEN / 128) * (HID / 128), 256, 0, stream>>>(
      attn, oh, ol, out, S_LEN, HID, ATT_N, HID / 128);
}

// Round 6
// 502.384 us; speedup vs baseline: 3.1953x; 1.1330x over previous
//
#include <hip/hip_runtime.h>
#include <hip/hip_bf16.h>
#include <cstdint>
#include <cstddef>

#define S_LEN 2048
#define HID   2560
#define NHQ   8
#define QKV_N 4096   // (NH + 2*NKV) * D
#define ATT_N 2048   // NH * D
#define WIN   1023
#define SCALE 0.0625f
#define NINF  -3.0e38f

typedef __attribute__((ext_vector_type(8))) short bf16x8;
typedef __attribute__((ext_vector_type(4))) float f32x4;

__device__ __forceinline__ unsigned bf_hi(float f) {
  unsigned u = __builtin_bit_cast(unsigned, f);
  return (u + 0x7FFFu + ((u >> 16) & 1u)) >> 16;   // RNE bf16 bits
}
__device__ __forceinline__ float bf_to_f(unsigned h) {
  return __builtin_bit_cast(float, h << 16);
}
__device__ __forceinline__ void g2l16(const void* g, void* l) {
  __builtin_amdgcn_global_load_lds((const __attribute__((address_space(1))) void*)g,
                                   (__attribute__((address_space(3))) void*)l,
                                   16, 0, 0);
}

// ---------- row-split: X[M][K] f32 -> Xh, Xl [M][K] bf16 ----------
__global__ __launch_bounds__(256) void split_rows(const float* __restrict__ X,
                                                  unsigned short* __restrict__ Xh,
                                                  unsigned short* __restrict__ Xl) {
  const size_t i = ((size_t)blockIdx.x * 256 + threadIdx.x) * 8;
  const float4 v0 = *(const float4*)(X + i);
  const float4 v1 = *(const float4*)(X + i + 4);
  const float f[8] = {v0.x, v0.y, v0.z, v0.w, v1.x, v1.y, v1.z, v1.w};
  unsigned hw[4], lw[4];
  #pragma unroll
  for (int j = 0; j < 4; ++j) {
    const unsigned h0 = bf_hi(f[2 * j]), h1 = bf_hi(f[2 * j + 1]);
    const float r0 = f[2 * j] - bf_to_f(h0), r1 = f[2 * j + 1] - bf_to_f(h1);
    hw[j] = h0 | (h1 << 16);
    lw[j] = bf_hi(r0) | (bf_hi(r1) << 16);
  }
  *(uint4*)(Xh + i) = make_uint4(hw[0], hw[1], hw[2], hw[3]);
  *(uint4*)(Xl + i) = make_uint4(lw[0], lw[1], lw[2], lw[3]);
}

// ---------- split+transpose: W[K][N] f32 -> Th/Tl[N][K] bf16 (hi/lo) ----------
__global__ __launch_bounds__(256) void split_transpose(const float* __restrict__ W,
                                                       unsigned short* __restrict__ Th,
                                                       unsigned short* __restrict__ Tl,
                                                       int K, int N) {
  __shared__ float tile[32][33];
  const int tid = threadIdx.x;
  const int kt = blockIdx.y * 32, nt = blockIdx.x * 32;
  {
    const int r = tid >> 3, c = (tid & 7) * 4;
    const float4 v = *(const float4*)(W + (size_t)(kt + r) * N + nt + c);
    tile[r][c] = v.x; tile[r][c + 1] = v.y; tile[r][c + 2] = v.z; tile[r][c + 3] = v.w;
  }
  __syncthreads();
  const int nl = tid >> 3, k = (tid & 7) * 4;
  unsigned hw[2], lw[2];
  #pragma unroll
  for (int j = 0; j < 2; ++j) {
    const float f0 = tile[k + 2 * j][nl], f1 = tile[k + 2 * j + 1][nl];
    const unsigned h0 = bf_hi(f0), h1 = bf_hi(f1);
    const float r0 = f0 - bf_to_f(h0), r1 = f1 - bf_to_f(h1);
    hw[j] = h0 | (h1 << 16);
    lw[j] = bf_hi(r0) | (bf_hi(r1) << 16);
  }
  *(uint2*)(Th + (size_t)(nt + nl) * K + kt + k) = make_uint2(hw[0], hw[1]);
  *(uint2*)(Tl + (size_t)(nt + nl) * K + kt + k) = make_uint2(lw[0], lw[1]);
}

// ---------- all-bf16 split GEMM: C[M][N] f32 = (Ah+Al)[M][K] @ (Bh+Bl)[N][K]^T ----------
// 128x128x32 tile, 256 thr = 4 waves (2x2), 4x4 16x16x32 frags, 3-term split MFMA.
// All four tiles staged via global_load_lds w=16; LDS linear [row][4 slots of 16B]
// with slot ^= (row>>1)&3 source swizzle -> 2-way (free) ds_read_b128 conflicts.
__global__ __launch_bounds__(256) void gemm_bf16_split(
    const unsigned short* __restrict__ Ah, const unsigned short* __restrict__ Al,
    const unsigned short* __restrict__ Bh, const unsigned short* __restrict__ Bl,
    float* __restrict__ C, int M, int N, int K, int nbx) {
  __shared__ __align__(16) unsigned short smem[16384];   // 4 tiles x 128x32 ush = 32 KB

  const int tid = threadIdx.x;
  int bid = blockIdx.x;
  const int cpx = gridDim.x >> 3;                 // grid % 8 == 0 for all calls
  bid = (bid & 7) * cpx + (bid >> 3);             // XCD-contiguous swizzle
  const int bm = (bid / nbx) * 128;
  const int bn = (bid % nbx) * 128;

  const int lane = tid & 63;
  const int wv = tid >> 6;
  const int wr = (wv >> 1) * 64;
  const int wc = (wv & 1) * 64;
  const int frow = lane & 15;
  const int g16 = lane >> 4;

  // staging slots: u0 = tid, u1 = tid+256; row = u>>2, lds slot = u&3,
  // global slot = (u&3) ^ ((row>>1)&3)
  const int u0 = tid, u1 = tid + 256;
  const int r0 = u0 >> 2, s0 = (u0 & 3) ^ ((r0 >> 1) & 3);
  const int r1 = u1 >> 2, s1 = (u1 & 3) ^ ((r1 >> 1) & 3);

  const unsigned short* a_h = Ah + (size_t)bm * K;
  const unsigned short* a_l = Al + (size_t)bm * K;
  const unsigned short* b_h = Bh + (size_t)bn * K;
  const unsigned short* b_l = Bl + (size_t)bn * K;

  unsigned short* d0 = smem + ((tid & ~63) << 3);          // wave-uniform dest bases
  unsigned short* d1 = smem + 2048 + ((tid & ~63) << 3);

  const int sx = (g16 ^ ((frow >> 1) & 3)) * 8;            // frag read slot (lane-const)

  f32x4 acc[4][4] = {};

  for (int k0 = 0; k0 < K; k0 += 32) {
    __syncthreads();   // previous iteration's fragment reads complete
    {
      const size_t o0 = (size_t)r0 * K + k0 + s0 * 8;
      const size_t o1 = (size_t)r1 * K + k0 + s1 * 8;
      g2l16(a_h + o0, d0);
      g2l16(a_h + o1, d1);
      g2l16(a_l + o0, d0 + 4096);
      g2l16(a_l + o1, d1 + 4096);
      g2l16(b_h + o0, d0 + 8192);
      g2l16(b_h + o1, d1 + 8192);
      g2l16(b_l + o0, d0 + 12288);
      g2l16(b_l + o1, d1 + 12288);
    }
    __syncthreads();   // drains vmcnt -> tiles ready

    bf16x8 ah[4], al[4], bh[4], bl[4];
    #pragma unroll
    for (int i = 0; i < 4; ++i) {
      ah[i] = *(const bf16x8*)&smem[(wr + i * 16 + frow) * 32 + sx];
      al[i] = *(const bf16x8*)&smem[4096 + (wr + i * 16 + frow) * 32 + sx];
      bh[i] = *(const bf16x8*)&smem[8192 + (wc + i * 16 + frow) * 32 + sx];
      bl[i] = *(const bf16x8*)&smem[12288 + (wc + i * 16 + frow) * 32 + sx];
    }
    #pragma unroll
    for (int i = 0; i < 4; ++i)
      #pragma unroll
      for (int j = 0; j < 4; ++j) {
        acc[i][j] = __builtin_amdgcn_mfma_f32_16x16x32_bf16(ah[i], bh[j], acc[i][j], 0, 0, 0);
        acc[i][j] = __builtin_amdgcn_mfma_f32_16x16x32_bf16(ah[i], bl[j], acc[i][j], 0, 0, 0);
        acc[i][j] = __builtin_amdgcn_mfma_f32_16x16x32_bf16(al[i], bh[j], acc[i][j], 0, 0, 0);
      }
  }

  #pragma unroll
  for (int i = 0; i < 4; ++i) {
    const int row0 = bm + wr + i * 16 + g16 * 4;
    #pragma unroll
    for (int j = 0; j < 4; ++j) {
      const int c = bn + wc + j * 16 + frow;
      #pragma unroll
      for (int r = 0; r < 4; ++r)
        C[(size_t)(row0 + r) * N + c] = acc[i][j][r];
    }
  }
}

// ------- RMSNorm + RoPE -> split-bf16 Q (scaled) / K buffers, MFMA layout -------
__global__ __launch_bounds__(256) void qk_norm_rope_split(
    const float* __restrict__ qkv, const float* __restrict__ cosp,
    const float* __restrict__ sinp, const float* __restrict__ qw,
    const float* __restrict__ kw,
    unsigned short* __restrict__ Qh, unsigned short* __restrict__ Ql,
    unsigned short* __restrict__ Kh, unsigned short* __restrict__ Kl) {
  const int lane = threadIdx.x & 63;
  const int wave = threadIdx.x >> 6;
  const int row  = blockIdx.x * 4 + wave;
  const int s    = row / 12;
  const int c    = row % 12;
  const float* p = qkv + (size_t)s * QKV_N + c * 256;

  float4 x = *(const float4*)(p + lane * 4);
  float ss = x.x * x.x + x.y * x.y + x.z * x.z + x.w * x.w;
  #pragma unroll
  for (int off = 32; off; off >>= 1) ss += __shfl_xor(ss, off);
  const float scale = rsqrtf(ss * (1.0f / 256.0f) + 1e-6f);

  const float* wp = (c < 8) ? qw : kw;
  float4 w4 = *(const float4*)(wp + lane * 4);
  float y0 = x.x * scale * (1.0f + w4.x);
  float y1 = x.y * scale * (1.0f + w4.y);
  float y2 = x.z * scale * (1.0f + w4.z);
  float y3 = x.w * scale * (1.0f + w4.w);

  float z0 = __shfl_xor(y0, 32);
  float z1 = __shfl_xor(y1, 32);
  float z2 = __shfl_xor(y2, 32);
  float z3 = __shfl_xor(y3, 32);
  const float sgn = (lane < 32) ? -1.0f : 1.0f;

  float4 c4 = *(const float4*)(cosp + (size_t)s * 256 + lane * 4);
  float4 s4 = *(const float4*)(sinp + (size_t)s * 256 + lane * 4);
  float o[4];
  o[0] = y0 * c4.x + sgn * z0 * s4.x;
  o[1] = y1 * c4.y + sgn * z1 * s4.y;
  o[2] = y2 * c4.z + sgn * z2 * s4.z;
  o[3] = y3 * c4.w + sgn * z3 * s4.w;

  const float mul = (c < 8) ? SCALE : 1.0f;   // fold softmax scale into Q
  #pragma unroll
  for (int j = 0; j < 4; ++j) o[j] *= mul;

  unsigned h[4], lo[4];
  #pragma unroll
  for (int j = 0; j < 4; ++j) {
    h[j] = bf_hi(o[j]);
    lo[j] = bf_hi(o[j] - bf_to_f(h[j]));
  }
  const size_t off = ((c < 8) ? ((size_t)c * S_LEN + s)
                              : ((size_t)(c - 8) * S_LEN + s)) * 256 + lane * 4;
  unsigned short* dh = (c < 8 ? Qh : Kh) + off;
  unsigned short* dl = (c < 8 ? Ql : Kl) + off;
  *(uint2*)dh = make_uint2(h[0] | (h[1] << 16), h[2] | (h[3] << 16));
  *(uint2*)dl = make_uint2(lo[0] | (lo[1] << 16), lo[2] | (lo[3] << 16));
}

// ---------- V split + transpose: qkv V region -> VT[kvh][256][2048] hi/lo ----------
__global__ __launch_bounds__(256) void v_split_transpose(
    const float* __restrict__ qkv,
    unsigned short* __restrict__ VTh, unsigned short* __restrict__ VTl) {
  __shared__ float tile[32][33];
  const int tid = threadIdx.x;
  const int s0 = blockIdx.x * 32, d0 = blockIdx.y * 32, kvh = blockIdx.z;
  {
    const int r = tid >> 3, c = (tid & 7) * 4;
    const float4 v = *(const float4*)(qkv + (size_t)(s0 + r) * QKV_N + 3072 + kvh * 256 + d0 + c);
    tile[r][c] = v.x; tile[r][c + 1] = v.y; tile[r][c + 2] = v.z; tile[r][c + 3] = v.w;
  }
  __syncthreads();
  const int dd = tid >> 3, sc = (tid & 7) * 4;
  unsigned h[4], lo[4];
  #pragma unroll
  for (int j = 0; j < 4; ++j) {
    const float f = tile[sc + j][dd];
    h[j] = bf_hi(f);
    lo[j] = bf_hi(f - bf_to_f(h[j]));
  }
  const size_t off = ((size_t)kvh * 256 + d0 + dd) * S_LEN + s0 + sc;
  *(uint2*)(VTh + off) = make_uint2(h[0] | (h[1] << 16), h[2] | (h[3] << 16));
  *(uint2*)(VTl + off) = make_uint2(lo[0] | (lo[1] << 16), lo[2] | (lo[3] << 16));
}

// ---------------- MFMA sliding-window GQA flash attention ----------------
// 2 waves x 16 q-rows per block; 1D grid of 512 decoded for XCD-kvh affinity
// (kvh j's blocks -> XCDs {2j,2j+1} under b%8 round-robin) so each XCD's L2
// holds exactly its kvh's 4 MB KV working set. Output written as split bf16.
#define PH_U  32768
#define PL_U  34048
__global__ __launch_bounds__(128, 2) void attn_mfma(
    const unsigned short* __restrict__ Qh, const unsigned short* __restrict__ Ql,
    const unsigned short* __restrict__ Kh, const unsigned short* __restrict__ Kl,
    const unsigned short* __restrict__ VTh, const unsigned short* __restrict__ VTl,
    unsigned short* __restrict__ Oh, unsigned short* __restrict__ Ol) {
  __shared__ __align__(16) unsigned short smem[35328];   // 70.7 KiB

  const int tid  = threadIdx.x;
  const int lane = tid & 63;
  const int wv   = __builtin_amdgcn_readfirstlane(tid >> 6);
  const int b    = blockIdx.x;
  const int xcd  = b & 7;
  const int kvh  = xcd >> 1;
  const int head = kvh * 2 + ((b >> 3) & 1);
  const int q0   = (((b >> 4) << 1) | (xcd & 1)) * 32;
  const int g16  = lane >> 4;      // 0..3
  const int c16  = lane & 15;      // 0..15

  // ---- Q fragments to registers (A-operand layout), hi/lo ----
  const int qrow = q0 + wv * 16 + c16;
  bf16x8 qh[8], ql[8];
  {
    const unsigned short* qph = Qh + ((size_t)head * S_LEN + qrow) * 256 + g16 * 8;
    const unsigned short* qpl = Ql + ((size_t)head * S_LEN + qrow) * 256 + g16 * 8;
    #pragma unroll
    for (int dc = 0; dc < 8; ++dc) {
      qh[dc] = *(const bf16x8*)(qph + dc * 32);
      ql[dc] = *(const bf16x8*)(qpl + dc * 32);
    }
  }

  f32x4 o_acc[16] = {};
  float m_run[4], l_run[4];
  #pragma unroll
  for (int r = 0; r < 4; ++r) { m_run[r] = NINF; l_run[r] = 0.0f; }

  const int rmin = q0 + wv * 16, rmax = rmin + 15;
  const unsigned short* kh_g  = Kh  + (size_t)kvh * S_LEN * 256;
  const unsigned short* kl_g  = Kl  + (size_t)kvh * S_LEN * 256;
  const unsigned short* vth_g = VTh + (size_t)kvh * 256 * S_LEN;
  const unsigned short* vtl_g = VTl + (size_t)kvh * 256 * S_LEN;

  const int kstart = (q0 > WIN) ? ((q0 - WIN) & ~31) : 0;
  const int kend   = q0 + 31;

  for (int t0 = kstart; t0 <= kend; t0 += 32) {
    // ---- stage K (32x256, slot^=(row&7)) and VT (256x32, slot^=((d>>1)&3)) ----
    {
      char* lbase = (char*)smem + ((tid & ~63) << 4);
      #pragma unroll
      for (int i = 0; i < 8; ++i) {                      // K hi
        const int uu = i * 128 + tid, row = uu >> 5, sl = uu & 31;
        g2l16(kh_g + (size_t)(t0 + row) * 256 + ((sl ^ (row & 7)) * 8),
              lbase + i * 2048);
      }
      #pragma unroll
      for (int i = 0; i < 8; ++i) {                      // K lo
        const int uu = i * 128 + tid, row = uu >> 5, sl = uu & 31;
        g2l16(kl_g + (size_t)(t0 + row) * 256 + ((sl ^ (row & 7)) * 8),
              lbase + 16384 + i * 2048);
      }
      #pragma unroll
      for (int i = 0; i < 8; ++i) {                      // VT hi
        const int uu = i * 128 + tid, d = uu >> 2, sl = uu & 3;
        g2l16(vth_g + (size_t)d * S_LEN + t0 + ((sl ^ ((d >> 1) & 3)) * 8),
              lbase + 32768 + i * 2048);
      }
      #pragma unroll
      for (int i = 0; i < 8; ++i) {                      // VT lo
        const int uu = i * 128 + tid, d = uu >> 2, sl = uu & 3;
        g2l16(vtl_g + (size_t)d * S_LEN + t0 + ((sl ^ ((d >> 1) & 3)) * 8),
              lbase + 49152 + i * 2048);
      }
    }
    __syncthreads();

    const bool active = (t0 <= rmax) && (t0 + 31 + WIN >= rmin);
    if (active) {
      // ---- QK^T: S[16q x 32k], 3-term split MFMA ----
      f32x4 sa[2] = {};
      #pragma unroll
      for (int t = 0; t < 2; ++t) {
        const int krow = t * 16 + c16;
        const int swz = krow & 7;
        #pragma unroll
        for (int dc = 0; dc < 8; ++dc) {
          const int sl = ((dc * 4 + g16) ^ swz) * 16;
          const bf16x8 kfh = *(const bf16x8*)((const char*)smem + krow * 512 + sl);
          const bf16x8 kfl = *(const bf16x8*)((const char*)smem + 16384 + krow * 512 + sl);
          sa[t] = __builtin_amdgcn_mfma_f32_16x16x32_bf16(qh[dc], kfh, sa[t], 0, 0, 0);
          sa[t] = __builtin_amdgcn_mfma_f32_16x16x32_bf16(qh[dc], kfl, sa[t], 0, 0, 0);
          sa[t] = __builtin_amdgcn_mfma_f32_16x16x32_bf16(ql[dc], kfh, sa[t], 0, 0, 0);
        }
      }

      // ---- online softmax ----
      const int k0c = t0 + c16;
      #pragma unroll
      for (int r = 0; r < 4; ++r) {
        const int q = rmin + g16 * 4 + r;
        const bool v0 = (k0c <= q) && (q - k0c <= WIN);
        const bool v1 = (k0c + 16 <= q) && (q - (k0c + 16) <= WIN);
        float s0 = v0 ? sa[0][r] : NINF;
        float s1 = v1 ? sa[1][r] : NINF;
        float mx = fmaxf(s0, s1);
        #pragma unroll
        for (int off = 8; off; off >>= 1) mx = fmaxf(mx, __shfl_xor(mx, off));
        const float m_new = fmaxf(m_run[r], mx);
        const float rs = __expf(m_run[r] - m_new);
        const float p0 = v0 ? __expf(s0 - m_new) : 0.0f;
        const float p1 = v1 ? __expf(s1 - m_new) : 0.0f;
        float psum = p0 + p1;
        #pragma unroll
        for (int off = 8; off; off >>= 1) psum += __shfl_xor(psum, off);
        l_run[r] = l_run[r] * rs + psum;
        m_run[r] = m_new;
        #pragma unroll
        for (int dt = 0; dt < 16; ++dt) o_acc[dt][r] *= rs;
        const int pro = wv * 640 + (g16 * 4 + r) * 40;
        const unsigned h0 = bf_hi(p0), h1 = bf_hi(p1);
        smem[PH_U + pro + c16]      = (unsigned short)h0;
        smem[PH_U + pro + 16 + c16] = (unsigned short)h1;
        smem[PL_U + pro + c16]      = (unsigned short)bf_hi(p0 - bf_to_f(h0));
        smem[PL_U + pro + 16 + c16] = (unsigned short)bf_hi(p1 - bf_to_f(h1));
      }

      // ---- PV ----
      const bf16x8 pah = *(const bf16x8*)&smem[PH_U + wv * 640 + c16 * 40 + g16 * 8];
      const bf16x8 pal = *(const bf16x8*)&smem[PL_U + wv * 640 + c16 * 40 + g16 * 8];
      #pragma unroll
      for (int dt = 0; dt < 16; ++dt) {
        const int vrow = dt * 16 + c16;
        const int sl = (g16 ^ ((vrow >> 1) & 3)) * 16;
        const bf16x8 vfh = *(const bf16x8*)((const char*)smem + 32768 + vrow * 64 + sl);
        const bf16x8 vfl = *(const bf16x8*)((const char*)smem + 49152 + vrow * 64 + sl);
        o_acc[dt] = __builtin_amdgcn_mfma_f32_16x16x32_bf16(pah, vfh, o_acc[dt], 0, 0, 0);
        o_acc[dt] = __builtin_amdgcn_mfma_f32_16x16x32_bf16(pah, vfl, o_acc[dt], 0, 0, 0);
        o_acc[dt] = __builtin_amdgcn_mfma_f32_16x16x32_bf16(pal, vfh, o_acc[dt], 0, 0, 0);
      }
    }
    __syncthreads();
  }

  // ---- epilogue: write split bf16 (GEMM2's A operand) ----
  #pragma unroll
  for (int r = 0; r < 4; ++r) {
    const float inv = 1.0f / l_run[r];
    const size_t rowo = (size_t)(rmin + g16 * 4 + r) * ATT_N + head * 256 + c16;
    #pragma unroll
    for (int dt = 0; dt < 16; ++dt) {
      const float o = o_acc[dt][r] * inv;
      const unsigned h = bf_hi(o);
      Oh[rowo + dt * 16] = (unsigned short)h;
      Ol[rowo + dt * 16] = (unsigned short)bf_hi(o - bf_to_f(h));
    }
  }
}

extern "C" void kernel_launch(void* const* d_in, const int* in_sizes, int n_in,
                              void* d_out, int out_size, void* d_ws, size_t ws_size,
                              hipStream_t stream) {
  const float* hs    = (const float*)d_in[0];
  const float* cosp  = (const float*)d_in[1];
  const float* sinp  = (const float*)d_in[2];
  const float* w_qkv = (const float*)d_in[3];   // (2560, 4096)
  const float* w_o   = (const float*)d_in[4];   // (2048, 2560)
  const float* qw    = (const float*)d_in[5];
  const float* kw    = (const float*)d_in[6];

  const size_t MB = 1024 * 1024;
  char* ws = (char*)d_ws;
  // workspace map (peak 72 MiB, liveness-overlaid):
  float* qkv = (float*)ws;                               // [0,32M): gemm1 out, dead after preps
  unsigned short* wh = (unsigned short*)(ws + 32 * MB);  // [32,52M): w_qkv hi, dead after gemm1
  unsigned short* wl = (unsigned short*)(ws + 52 * MB);  // [52,72M)
  unsigned short* Qh = (unsigned short*)(ws + 32 * MB);  // [32,40M)
  unsigned short* Ql = (unsigned short*)(ws + 40 * MB);  // [40,48M)
  unsigned short* Kh = (unsigned short*)(ws + 48 * MB);  // [48,52M)
  unsigned short* Kl = (unsigned short*)(ws + 52 * MB);  // [52,56M)
  unsigned short* VTh = (unsigned short*)(ws + 56 * MB); // [56,60M)
  unsigned short* VTl = (unsigned short*)(ws + 60 * MB); // [60,64M)
  unsigned short* Oh = (unsigned short*)ws;              // [0,8M): qkv dead by then
  unsigned short* Ol = (unsigned short*)(ws + 8 * MB);   // [8,16M)
  unsigned short* oh = (unsigned short*)(ws + 16 * MB);  // [16,26M): after attn
  unsigned short* ol = (unsigned short*)(ws + 26 * MB);  // [26,36M)
  // hs split lives in d_out (dead until final GEMM writes it); exact fit 20.97 MB
  unsigned short* Ahs = (unsigned short*)d_out;
  unsigned short* Als = Ahs + (size_t)S_LEN * HID;
  float* out = (float*)d_out;

  // 1) hs -> split bf16 (into d_out scratch)
  split_rows<<<(S_LEN * HID) / (256 * 8), 256, 0, stream>>>(hs, Ahs, Als);
  // 2) w_qkv -> split^T
  split_transpose<<<dim3(QKV_N / 32, HID / 32), 256, 0, stream>>>(
      w_qkv, wh, wl, HID, QKV_N);
  // 3) qkv = hs @ w_qkv  (all-bf16 split MFMA, g2l16-staged)
  gemm_bf16_split<<<(S_LEN / 128) * (QKV_N / 128), 256, 0, stream>>>(
      Ahs, Als, wh, wl, qkv, S_LEN, QKV_N, HID, QKV_N / 128);
  // 4) norm+rope -> Q/K split bf16 (SCALE folded into Q)
  qk_norm_rope_split<<<(S_LEN * 12) / 4, 256, 0, stream>>>(
      qkv, cosp, sinp, qw, kw, Qh, Ql, Kh, Kl);
  // 5) V -> split + transpose
  v_split_transpose<<<dim3(S_LEN / 32, 256 / 32, 4), 256, 0, stream>>>(
      qkv, VTh, VTl);
  // 6) MFMA flash attention (XCD-affine), writes split-bf16 output
  attn_mfma<<<512, 128, 0, stream>>>(Qh, Ql, Kh, Kl, VTh, VTl, Oh, Ol);
  // 7) w_o -> split^T (after attn: reuses dead Q/qkv regions)
  split_transpose<<<dim3(HID / 32, ATT_N / 32), 256, 0, stream>>>(
      w_o, oh, ol, ATT_N, HID);
  // 8) out = attn @ w_o
  gemm_bf16_split<<<(S_LEN / 128) * (HID / 128), 256, 0, stream>>>(
      Oh, Ol, oh, ol, out, S_LEN, HID, ATT_N, HID / 128);
}